// Round 2
// baseline (1177.252 us; speedup 1.0000x reference)
//
#include <hip/hip_runtime.h>
#include <hip/hip_bf16.h>
#include <math.h>
#include <stdint.h>

using bf16 = __hip_bfloat16;
typedef __attribute__((ext_vector_type(4))) float f32x4;
typedef __attribute__((ext_vector_type(8))) short s16x8;

#define MFMA16(a, b, c) __builtin_amdgcn_mfma_f32_16x16x32_bf16(a, b, c, 0, 0, 0)

__device__ __forceinline__ void gload_lds16(const void* g, void* l) {
    __builtin_amdgcn_global_load_lds(
        (const __attribute__((address_space(1))) void*)g,
        (__attribute__((address_space(3))) void*)l, 16, 0, 0);
}

// ---------------- fp32 -> bf16 straight convert (8 elems/thread) ----------------
struct alignas(16) bf16x8s { bf16 v[8]; };

__global__ void cvt_f32_bf16(const float* __restrict__ in, bf16* __restrict__ out, long n) {
    long i = ((long)blockIdx.x * 256 + threadIdx.x) * 8;
    if (i >= n) return;
    float4 a = *(const float4*)(in + i);
    float4 b = *(const float4*)(in + i + 4);
    bf16x8s r;
    r.v[0] = __float2bfloat16(a.x); r.v[1] = __float2bfloat16(a.y);
    r.v[2] = __float2bfloat16(a.z); r.v[3] = __float2bfloat16(a.w);
    r.v[4] = __float2bfloat16(b.x); r.v[5] = __float2bfloat16(b.y);
    r.v[6] = __float2bfloat16(b.z); r.v[7] = __float2bfloat16(b.w);
    *(bf16x8s*)(out + i) = r;
}

// ---------------- fp32 [K][N] -> bf16 [N][K] transpose-convert ----------------
__global__ void transpose_cvt(const float* __restrict__ W, bf16* __restrict__ Wt, int K, int N) {
    __shared__ bf16 t[32][33];
    int tx = threadIdx.x & 31, ty = threadIdx.x >> 5;
    int n0 = blockIdx.x * 32, k0 = blockIdx.y * 32;
    #pragma unroll
    for (int r = ty; r < 32; r += 8)
        t[r][tx] = __float2bfloat16(W[(size_t)(k0 + r) * N + n0 + tx]);
    __syncthreads();
    #pragma unroll
    for (int r = ty; r < 32; r += 8)
        Wt[(size_t)(n0 + r) * K + k0 + tx] = t[tx][r];
}

// ---------------- GEMM: C[M,N] = A[M,K] * Bt[N,K]^T, bf16 in, fp32 acc ----------------
// EPI 0: store bf16.  EPI 1: bias + exact gelu -> bf16.  EPI 2: bias + residual -> fp32.
template <int EPI>
__global__ __launch_bounds__(256) void gemm_bt(
    const bf16* __restrict__ A, const bf16* __restrict__ Bt,
    void* __restrict__ C, const float* __restrict__ bias,
    const float* __restrict__ resid, int M, int N, int K)
{
    __shared__ __align__(16) bf16 As[128 * 32];
    __shared__ __align__(16) bf16 Bs[128 * 32];
    const int tid = threadIdx.x;
    const int wid = tid >> 6, lane = tid & 63;
    const int quad = lane >> 4, l16 = lane & 15;
    const int bm = blockIdx.x * 128, bn = blockIdx.y * 128;
    const int wm = (wid >> 1) * 64, wn = (wid & 1) * 64;

    f32x4 acc[4][4] = {};

    for (int k0 = 0; k0 < K; k0 += 32) {
        __syncthreads();
        #pragma unroll
        for (int c = 0; c < 2; ++c) {
            int choff = (wid * 2 + c) << 10;       // wave-uniform chunk base (bytes)
            int off = choff + lane * 16;           // per-lane byte position in tile
            int row = off >> 6;                    // 64 B per row (32 bf16)
            int col = (off & 63) >> 1;             // element col
            gload_lds16(A  + (size_t)(bm + row) * K + k0 + col, (char*)As + choff);
            gload_lds16(Bt + (size_t)(bn + row) * K + k0 + col, (char*)Bs + choff);
        }
        __syncthreads();
        s16x8 af[4], bfr[4];
        #pragma unroll
        for (int mt = 0; mt < 4; ++mt)
            af[mt] = *(const s16x8*)(As + (wm + mt * 16 + l16) * 32 + quad * 8);
        #pragma unroll
        for (int nt = 0; nt < 4; ++nt)
            bfr[nt] = *(const s16x8*)(Bs + (wn + nt * 16 + l16) * 32 + quad * 8);
        #pragma unroll
        for (int mt = 0; mt < 4; ++mt)
            #pragma unroll
            for (int nt = 0; nt < 4; ++nt)
                acc[mt][nt] = MFMA16(af[mt], bfr[nt], acc[mt][nt]);
    }

    #pragma unroll
    for (int mt = 0; mt < 4; ++mt) {
        #pragma unroll
        for (int nt = 0; nt < 4; ++nt) {
            #pragma unroll
            for (int r = 0; r < 4; ++r) {
                int row = bm + wm + mt * 16 + quad * 4 + r;   // C/D: row = quad*4+reg (m89)
                int col = bn + wn + nt * 16 + l16;            //      col = lane&15
                float v = acc[mt][nt][r];
                if (EPI == 0) {
                    ((bf16*)C)[(size_t)row * N + col] = __float2bfloat16(v);
                } else if (EPI == 1) {
                    float xx = v + bias[col];
                    float g = 0.5f * xx * (1.0f + erff(xx * 0.7071067811865475f));
                    ((bf16*)C)[(size_t)row * N + col] = __float2bfloat16(g);
                } else {
                    ((float*)C)[(size_t)row * N + col] =
                        v + bias[col] + resid[(size_t)row * N + col];
                }
            }
        }
    }
}

// ---------------- RoPE: pairs (2j,2j+1) -> outputs j and j+D/2 ----------------
// NOTE: reference's _rope uses L = x.shape[0] = B, so cos/sin are indexed by
// the BATCH index (broadcast over sequence), not the sequence position.
__global__ void rope_kernel(const bf16* __restrict__ in, bf16* __restrict__ out,
                            const float* __restrict__ sn, const float* __restrict__ cs,
                            int S, int D) {
    int row = blockIdx.x;
    int pos = row / S;                 // batch index — matches reference broadcast
    const int half = D >> 1;
    const bf16* r = in + (size_t)row * D;
    bf16* o = out + (size_t)row * D;
    for (int j = threadIdx.x; j < half; j += 256) {
        uint32_t pr = *(const uint32_t*)(r + 2 * j);
        float x1 = __uint_as_float(pr << 16);
        float x2 = __uint_as_float(pr & 0xffff0000u);
        float c = cs[(size_t)pos * half + j], s = sn[(size_t)pos * half + j];
        o[j]        = __float2bfloat16(x1 * c - x2 * s);
        o[half + j] = __float2bfloat16(x1 * s + x2 * c);
    }
}

// ---------------- V transpose per head: v[b,s,h,d] -> vt[bh, d, s] ----------------
__global__ void vtrans_kernel(const bf16* __restrict__ v, bf16* __restrict__ vt,
                              int S, int D, int H) {
    __shared__ bf16 t[32][33];
    int bh = blockIdx.z, b = bh >> 4, h = bh & 15;
    int s0 = blockIdx.x * 32, d0 = blockIdx.y * 32;
    int tx = threadIdx.x & 31, ty = threadIdx.x >> 5;
    #pragma unroll
    for (int r = ty; r < 32; r += 8)
        t[r][tx] = v[(size_t)(b * S + s0 + r) * D + h * 128 + d0 + tx];
    __syncthreads();
    #pragma unroll
    for (int r = ty; r < 32; r += 8)
        vt[((size_t)bh * 128 + d0 + r) * S + s0 + tx] = t[tx][r];
}

// ---------------- Flash attention: one block = one (b,h) x 128-row q-tile ----------------
__global__ __launch_bounds__(256) void attn_kernel(
    const bf16* __restrict__ q, const bf16* __restrict__ k, const bf16* __restrict__ vt,
    float* __restrict__ o, int S, int D, int H)
{
    __shared__ __align__(16) bf16 Ks[64 * 128];   // [kj][d]
    __shared__ __align__(16) bf16 Vs[128 * 64];   // [d][kj]  (from vt)
    __shared__ __align__(16) bf16 Ps[128 * 72];   // [qi][kj] padded to 72
    const int tid = threadIdx.x, wid = tid >> 6, lane = tid & 63;
    const int quad = lane >> 4, l16 = lane & 15;
    const int qt = blockIdx.x;
    const int bh = blockIdx.y, b = bh >> 4, h = bh & 15;
    const float scale = 0.08838834764831845f;   // 1/sqrt(128)

    // Q fragments straight from global (A-operand layout: row=lane&15, k=quad*8+j)
    s16x8 qf[2][4];
    const bf16* qbase = q + ((size_t)(b * S + qt * 128 + wid * 32)) * D + h * 128;
    #pragma unroll
    for (int mt = 0; mt < 2; ++mt)
        #pragma unroll
        for (int ks = 0; ks < 4; ++ks)
            qf[mt][ks] = *(const s16x8*)(qbase + (size_t)(mt * 16 + l16) * D + ks * 32 + quad * 8);

    f32x4 oacc[2][8] = {};
    float mstate[2][4], lstate[2][4];
    #pragma unroll
    for (int mt = 0; mt < 2; ++mt)
        #pragma unroll
        for (int r = 0; r < 4; ++r) { mstate[mt][r] = -INFINITY; lstate[mt][r] = 0.f; }

    const int nchunks = 2 * qt + 2;
    const bf16* kb0 = k + (size_t)(b * S) * D + h * 128;
    const bf16* vb0 = vt + (size_t)bh * 128 * S;

    for (int kc = 0; kc < nchunks; ++kc) {
        __syncthreads();
        #pragma unroll
        for (int c = 0; c < 4; ++c) {
            int choff = ((wid * 4 + c) << 10);
            int off = choff + lane * 16;
            int row = off >> 8, col = (off & 255) >> 1;     // Ks: 256 B rows
            gload_lds16(kb0 + (size_t)(kc * 64 + row) * D + col, (char*)Ks + choff);
            int rowv = off >> 7, colv = (off & 127) >> 1;   // Vs: 128 B rows
            gload_lds16(vb0 + (size_t)rowv * S + kc * 64 + colv, (char*)Vs + choff);
        }
        __syncthreads();

        // S = Q K^T  (wave owns 32 q-rows x 64 cols)
        f32x4 sacc[2][4] = {};
        #pragma unroll
        for (int ks = 0; ks < 4; ++ks) {
            s16x8 kf[4];
            #pragma unroll
            for (int nt = 0; nt < 4; ++nt)
                kf[nt] = *(const s16x8*)(Ks + (nt * 16 + l16) * 128 + ks * 32 + quad * 8);
            #pragma unroll
            for (int mt = 0; mt < 2; ++mt)
                #pragma unroll
                for (int nt = 0; nt < 4; ++nt)
                    sacc[mt][nt] = MFMA16(qf[mt][ks], kf[nt], sacc[mt][nt]);
        }

        const bool need_mask = (kc >= 2 * qt);
        #pragma unroll
        for (int mt = 0; mt < 2; ++mt)
            #pragma unroll
            for (int nt = 0; nt < 4; ++nt)
                #pragma unroll
                for (int r = 0; r < 4; ++r) {
                    float vv = sacc[mt][nt][r] * scale;
                    if (need_mask) {
                        int rowg = qt * 128 + wid * 32 + mt * 16 + quad * 4 + r;
                        int colg = kc * 64 + nt * 16 + l16;
                        if (colg > rowg) vv = -INFINITY;
                    }
                    sacc[mt][nt][r] = vv;
                }

        // online softmax per (mt, reg): row stats live on the 16-lane col group
        #pragma unroll
        for (int mt = 0; mt < 2; ++mt) {
            #pragma unroll
            for (int r = 0; r < 4; ++r) {
                float mx = fmaxf(fmaxf(sacc[mt][0][r], sacc[mt][1][r]),
                                 fmaxf(sacc[mt][2][r], sacc[mt][3][r]));
                #pragma unroll
                for (int d2 = 1; d2 < 16; d2 <<= 1) mx = fmaxf(mx, __shfl_xor(mx, d2, 64));
                float mnew = fmaxf(mstate[mt][r], mx);
                float alpha = __expf(mstate[mt][r] - mnew);
                float rs = 0.f;
                #pragma unroll
                for (int nt = 0; nt < 4; ++nt) {
                    float p = __expf(sacc[mt][nt][r] - mnew);
                    sacc[mt][nt][r] = p;
                    rs += p;
                }
                #pragma unroll
                for (int d2 = 1; d2 < 16; d2 <<= 1) rs += __shfl_xor(rs, d2, 64);
                lstate[mt][r] = lstate[mt][r] * alpha + rs;
                mstate[mt][r] = mnew;
                #pragma unroll
                for (int nt = 0; nt < 8; ++nt) oacc[mt][nt][r] *= alpha;
            }
        }

        // P -> LDS (C/D layout scatter), then re-read as A-operand
        #pragma unroll
        for (int mt = 0; mt < 2; ++mt)
            #pragma unroll
            for (int nt = 0; nt < 4; ++nt)
                #pragma unroll
                for (int r = 0; r < 4; ++r)
                    Ps[(wid * 32 + mt * 16 + quad * 4 + r) * 72 + nt * 16 + l16] =
                        __float2bfloat16(sacc[mt][nt][r]);

        #pragma unroll
        for (int ks = 0; ks < 2; ++ks) {
            s16x8 pf[2];
            #pragma unroll
            for (int mt = 0; mt < 2; ++mt)
                pf[mt] = *(const s16x8*)(Ps + (wid * 32 + mt * 16 + l16) * 72 + ks * 32 + quad * 8);
            #pragma unroll
            for (int nt = 0; nt < 8; ++nt) {
                s16x8 vf = *(const s16x8*)(Vs + (nt * 16 + l16) * 64 + ks * 32 + quad * 8);
                #pragma unroll
                for (int mt = 0; mt < 2; ++mt)
                    oacc[mt][nt] = MFMA16(pf[mt], vf, oacc[mt][nt]);
            }
        }
    }

    #pragma unroll
    for (int mt = 0; mt < 2; ++mt) {
        float inv[4];
        #pragma unroll
        for (int r = 0; r < 4; ++r) inv[r] = 1.0f / lstate[mt][r];
        #pragma unroll
        for (int nt = 0; nt < 8; ++nt)
            #pragma unroll
            for (int r = 0; r < 4; ++r) {
                int rowg = qt * 128 + wid * 32 + mt * 16 + quad * 4 + r;
                int colg = h * 128 + nt * 16 + l16;
                o[(size_t)(b * S + rowg) * D + colg] = oacc[mt][nt][r] * inv[r];
            }
    }
}

// ---------------- LayerNorm over D=2048 (optional add, dual f32/bf16 out) ----------------
__global__ __launch_bounds__(256) void ln_kernel(
    const float* __restrict__ a, const float* __restrict__ b,
    float* __restrict__ outf, bf16* __restrict__ outb, int D)
{
    int row = blockIdx.x;
    const float* pa = a + (size_t)row * D;
    const float* pb = b ? b + (size_t)row * D : nullptr;
    float v[8];
    float sum = 0.f, sq = 0.f;
    #pragma unroll
    for (int u = 0; u < 8; ++u) {
        int j = threadIdx.x + u * 256;
        float x = pa[j];
        if (pb) x += pb[j];
        v[u] = x; sum += x; sq += x * x;
    }
    #pragma unroll
    for (int off = 32; off > 0; off >>= 1) {
        sum += __shfl_down(sum, off, 64);
        sq  += __shfl_down(sq,  off, 64);
    }
    __shared__ float red[8];
    int wid = threadIdx.x >> 6, lane = threadIdx.x & 63;
    if (lane == 0) { red[wid] = sum; red[4 + wid] = sq; }
    __syncthreads();
    sum = red[0] + red[1] + red[2] + red[3];
    sq  = red[4] + red[5] + red[6] + red[7];
    float mean = sum / D;
    float var = sq / D - mean * mean;
    float rstd = rsqrtf(fmaxf(var, 0.f) + 1e-5f);
    float* pof = outf ? outf + (size_t)row * D : nullptr;
    bf16* pob = outb ? outb + (size_t)row * D : nullptr;
    #pragma unroll
    for (int u = 0; u < 8; ++u) {
        int j = threadIdx.x + u * 256;
        float y = (v[u] - mean) * rstd;
        if (pof) pof[j] = y;
        if (pob) pob[j] = __float2bfloat16(y);
    }
}

// ---------------- launch ----------------
extern "C" void kernel_launch(void* const* d_in, const int* in_sizes, int n_in,
                              void* d_out, int out_size, void* d_ws, size_t ws_size,
                              hipStream_t stream) {
    const float* x  = (const float*)d_in[0];
    const float* Wq = (const float*)d_in[1];
    const float* Wk = (const float*)d_in[2];
    const float* Wv = (const float*)d_in[3];
    const float* W1 = (const float*)d_in[4];
    const float* b1 = (const float*)d_in[5];
    const float* W2 = (const float*)d_in[6];
    const float* b2 = (const float*)d_in[7];
    const float* sn = (const float*)d_in[8];
    const float* cs = (const float*)d_in[9];

    const int B = 2, S = 2048, D = 2048, H = 16, Dff = 8192;
    const int M = B * S;                       // 4096
    char* ws = (char*)d_ws;

    const size_t SB = (size_t)M * D * 2;       // 16 MB bf16 [M][D] slot
    const size_t o_xb   = 0;
    const size_t o_Wqt  = SB;                  //  16,777,216
    const size_t o_Wkt  = o_Wqt + (size_t)D * D * 2;
    const size_t o_Wvt  = o_Wkt + (size_t)D * D * 2;
    const size_t o_qraw = o_Wvt + (size_t)D * D * 2;   // 41,943,040
    const size_t o_kraw = o_qraw + SB;
    const size_t o_vb   = o_qraw + 2 * SB;             // 75,497,472
    const size_t o_qr   = 0;                  // reuse xb (dead after QKV gemms)
    const size_t o_kr   = SB;                 // reuse Wq/Wk bf16 region (dead)
    const size_t o_attn = o_qraw;             // fp32, reuse qraw+kraw (dead after rope)
    const size_t o_vt   = o_vb + SB;          // 92,274,688
    const size_t o_outb = o_vt;               // reuse vt (dead after attention)
    const size_t o_outf = 0;                  // fp32, reuse qr+kr (dead after attention)
    const size_t o_W1t  = o_vt + SB;          // 109,051,904
    const size_t o_W2t  = o_W1t + (size_t)D * Dff * 2;
    const size_t o_h    = o_W2t + (size_t)D * Dff * 2; // + 64 MB -> ~240 MB total

    // 1. conversions
    long nx = (long)M * D;
    cvt_f32_bf16<<<nx / 2048, 256, 0, stream>>>(x, (bf16*)(ws + o_xb), nx);
    transpose_cvt<<<dim3(D / 32, D / 32), 256, 0, stream>>>(Wq, (bf16*)(ws + o_Wqt), D, D);
    transpose_cvt<<<dim3(D / 32, D / 32), 256, 0, stream>>>(Wk, (bf16*)(ws + o_Wkt), D, D);
    transpose_cvt<<<dim3(D / 32, D / 32), 256, 0, stream>>>(Wv, (bf16*)(ws + o_Wvt), D, D);
    transpose_cvt<<<dim3(Dff / 32, D / 32), 256, 0, stream>>>(W1, (bf16*)(ws + o_W1t), D, Dff);
    transpose_cvt<<<dim3(D / 32, Dff / 32), 256, 0, stream>>>(W2, (bf16*)(ws + o_W2t), Dff, D);

    // 2. QKV projections (bf16 out)
    dim3 gqkv(M / 128, D / 128);
    gemm_bt<0><<<gqkv, 256, 0, stream>>>((bf16*)(ws + o_xb), (bf16*)(ws + o_Wqt),
                                         ws + o_qraw, nullptr, nullptr, M, D, D);
    gemm_bt<0><<<gqkv, 256, 0, stream>>>((bf16*)(ws + o_xb), (bf16*)(ws + o_Wkt),
                                         ws + o_kraw, nullptr, nullptr, M, D, D);
    gemm_bt<0><<<gqkv, 256, 0, stream>>>((bf16*)(ws + o_xb), (bf16*)(ws + o_Wvt),
                                         ws + o_vb, nullptr, nullptr, M, D, D);

    // 3. RoPE + V transpose
    rope_kernel<<<M, 256, 0, stream>>>((bf16*)(ws + o_qraw), (bf16*)(ws + o_qr), sn, cs, S, D);
    rope_kernel<<<M, 256, 0, stream>>>((bf16*)(ws + o_kraw), (bf16*)(ws + o_kr), sn, cs, S, D);
    vtrans_kernel<<<dim3(S / 32, 4, B * H), 256, 0, stream>>>((bf16*)(ws + o_vb),
                                                              (bf16*)(ws + o_vt), S, D, H);

    // 4. causal flash attention
    attn_kernel<<<dim3(S / 128, B * H), 256, 0, stream>>>(
        (bf16*)(ws + o_qr), (bf16*)(ws + o_kr), (bf16*)(ws + o_vt),
        (float*)(ws + o_attn), S, D, H);

    // 5. LN(attn + x)
    ln_kernel<<<M, 256, 0, stream>>>((float*)(ws + o_attn), x,
                                     (float*)(ws + o_outf), (bf16*)(ws + o_outb), D);

    // 6. FFN1: gelu(out @ W1 + b1) -> bf16 h
    gemm_bt<1><<<dim3(M / 128, Dff / 128), 256, 0, stream>>>(
        (bf16*)(ws + o_outb), (bf16*)(ws + o_W1t), ws + o_h, b1, nullptr, M, Dff, D);

    // 7. FFN2: h @ W2 + b2 + out -> fp32 into d_out
    gemm_bt<2><<<dim3(M / 128, D / 128), 256, 0, stream>>>(
        (bf16*)(ws + o_h), (bf16*)(ws + o_W2t), d_out, b2, (float*)(ws + o_outf), M, D, Dff);

    // 8. LN2 in place on d_out
    ln_kernel<<<M, 256, 0, stream>>>((float*)d_out, nullptr, (float*)d_out, nullptr, D);
}

// Round 3
// 1014.261 us; speedup vs baseline: 1.1607x; 1.1607x over previous
//
#include <hip/hip_runtime.h>
#include <hip/hip_bf16.h>
#include <math.h>
#include <stdint.h>

using bf16 = __hip_bfloat16;
typedef __attribute__((ext_vector_type(4))) float f32x4;
typedef __attribute__((ext_vector_type(8))) short s16x8;

#define MFMA16(a, b, c) __builtin_amdgcn_mfma_f32_16x16x32_bf16(a, b, c, 0, 0, 0)

__device__ __forceinline__ void gload_lds16(const void* g, void* l) {
    __builtin_amdgcn_global_load_lds(
        (const __attribute__((address_space(1))) void*)g,
        (__attribute__((address_space(3))) void*)l, 16, 0, 0);
}

// ---------------- fp32 -> bf16 straight convert (8 elems/thread) ----------------
struct alignas(16) bf16x8s { bf16 v[8]; };

__global__ void cvt_f32_bf16(const float* __restrict__ in, bf16* __restrict__ out, long n) {
    long i = ((long)blockIdx.x * 256 + threadIdx.x) * 8;
    if (i >= n) return;
    float4 a = *(const float4*)(in + i);
    float4 b = *(const float4*)(in + i + 4);
    bf16x8s r;
    r.v[0] = __float2bfloat16(a.x); r.v[1] = __float2bfloat16(a.y);
    r.v[2] = __float2bfloat16(a.z); r.v[3] = __float2bfloat16(a.w);
    r.v[4] = __float2bfloat16(b.x); r.v[5] = __float2bfloat16(b.y);
    r.v[6] = __float2bfloat16(b.z); r.v[7] = __float2bfloat16(b.w);
    *(bf16x8s*)(out + i) = r;
}

// ---------------- fp32 [K][N] -> bf16 [N][K] transpose-convert ----------------
__global__ void transpose_cvt(const float* __restrict__ W, bf16* __restrict__ Wt, int K, int N) {
    __shared__ bf16 t[32][33];
    int tx = threadIdx.x & 31, ty = threadIdx.x >> 5;
    int n0 = blockIdx.x * 32, k0 = blockIdx.y * 32;
    #pragma unroll
    for (int r = ty; r < 32; r += 8)
        t[r][tx] = __float2bfloat16(W[(size_t)(k0 + r) * N + n0 + tx]);
    __syncthreads();
    #pragma unroll
    for (int r = ty; r < 32; r += 8)
        Wt[(size_t)(n0 + r) * K + k0 + tx] = t[tx][r];
}

// ---------------- GEMM: C[M,N] = A[M,K] * Bt[N,K]^T, bf16 in, fp32 acc ----------------
template <int EPI>
__global__ __launch_bounds__(256) void gemm_bt(
    const bf16* __restrict__ A, const bf16* __restrict__ Bt,
    void* __restrict__ C, const float* __restrict__ bias,
    const float* __restrict__ resid, int M, int N, int K)
{
    __shared__ __align__(16) bf16 As[128 * 32];
    __shared__ __align__(16) bf16 Bs[128 * 32];
    const int tid = threadIdx.x;
    const int wid = tid >> 6, lane = tid & 63;
    const int quad = lane >> 4, l16 = lane & 15;
    const int bm = blockIdx.x * 128, bn = blockIdx.y * 128;
    const int wm = (wid >> 1) * 64, wn = (wid & 1) * 64;

    f32x4 acc[4][4] = {};

    for (int k0 = 0; k0 < K; k0 += 32) {
        __syncthreads();
        #pragma unroll
        for (int c = 0; c < 2; ++c) {
            int choff = (wid * 2 + c) << 10;
            int off = choff + lane * 16;
            int row = off >> 6;
            int col = (off & 63) >> 1;
            gload_lds16(A  + (size_t)(bm + row) * K + k0 + col, (char*)As + choff);
            gload_lds16(Bt + (size_t)(bn + row) * K + k0 + col, (char*)Bs + choff);
        }
        __syncthreads();
        s16x8 af[4], bfr[4];
        #pragma unroll
        for (int mt = 0; mt < 4; ++mt)
            af[mt] = *(const s16x8*)(As + (wm + mt * 16 + l16) * 32 + quad * 8);
        #pragma unroll
        for (int nt = 0; nt < 4; ++nt)
            bfr[nt] = *(const s16x8*)(Bs + (wn + nt * 16 + l16) * 32 + quad * 8);
        #pragma unroll
        for (int mt = 0; mt < 4; ++mt)
            #pragma unroll
            for (int nt = 0; nt < 4; ++nt)
                acc[mt][nt] = MFMA16(af[mt], bfr[nt], acc[mt][nt]);
    }

    #pragma unroll
    for (int mt = 0; mt < 4; ++mt) {
        #pragma unroll
        for (int nt = 0; nt < 4; ++nt) {
            #pragma unroll
            for (int r = 0; r < 4; ++r) {
                int row = bm + wm + mt * 16 + quad * 4 + r;
                int col = bn + wn + nt * 16 + l16;
                float v = acc[mt][nt][r];
                if (EPI == 0) {
                    ((bf16*)C)[(size_t)row * N + col] = __float2bfloat16(v);
                } else if (EPI == 1) {
                    float xx = v + bias[col];
                    float g = 0.5f * xx * (1.0f + erff(xx * 0.7071067811865475f));
                    ((bf16*)C)[(size_t)row * N + col] = __float2bfloat16(g);
                } else {
                    ((float*)C)[(size_t)row * N + col] =
                        v + bias[col] + resid[(size_t)row * N + col];
                }
            }
        }
    }
}

// ---------------- RoPE (reference indexes sin/cos by BATCH, not position) ----------------
__global__ void rope_kernel(const bf16* __restrict__ in, bf16* __restrict__ out,
                            const float* __restrict__ sn, const float* __restrict__ cs,
                            int S, int D) {
    int row = blockIdx.x;
    int pos = row / S;                 // batch index — matches reference broadcast
    const int half = D >> 1;
    const bf16* r = in + (size_t)row * D;
    bf16* o = out + (size_t)row * D;
    for (int j = threadIdx.x; j < half; j += 256) {
        uint32_t pr = *(const uint32_t*)(r + 2 * j);
        float x1 = __uint_as_float(pr << 16);
        float x2 = __uint_as_float(pr & 0xffff0000u);
        float c = cs[(size_t)pos * half + j], s = sn[(size_t)pos * half + j];
        o[j]        = __float2bfloat16(x1 * c - x2 * s);
        o[half + j] = __float2bfloat16(x1 * s + x2 * c);
    }
}

// ---------------- V transpose per head: v[b,s,h,d] -> vt[bh, d, s] ----------------
__global__ void vtrans_kernel(const bf16* __restrict__ v, bf16* __restrict__ vt,
                              int S, int D, int H) {
    __shared__ bf16 t[32][33];
    int bh = blockIdx.z, b = bh >> 4, h = bh & 15;
    int s0 = blockIdx.x * 32, d0 = blockIdx.y * 32;
    int tx = threadIdx.x & 31, ty = threadIdx.x >> 5;
    #pragma unroll
    for (int r = ty; r < 32; r += 8)
        t[r][tx] = v[(size_t)(b * S + s0 + r) * D + h * 128 + d0 + tx];
    __syncthreads();
    #pragma unroll
    for (int r = ty; r < 32; r += 8)
        vt[((size_t)bh * 128 + d0 + r) * S + s0 + tx] = t[tx][r];
}

// ---------------- Flash attention, transposed-score form ----------------
// Block: 64 q-rows (wave w owns q = qt*64 + w*16 + l16), bh. Chunk = 64 k.
// S^T = K·Q^T (K = A-operand from LDS, Q = B-operand in regs) so the softmax
// reduction over k is in-lane (16 vals) + 2 shfls. O^T = V^T·P^T accumulated
// in C/D layout, transposed via LDS once at the end.
// LDS: Ks 16384 + Vs 16384 + Ps 8192 = 40960 B exactly -> 4 blocks/CU.
__global__ __launch_bounds__(256, 4) void attn_kernel(
    const bf16* __restrict__ q, const bf16* __restrict__ k, const bf16* __restrict__ vt,
    float* __restrict__ o, int S, int D, int H)
{
    __shared__ __align__(16) char smem[40960];
    bf16* Ks = (bf16*)smem;                 // [64 k][128 d], 16B-block XOR swizzle
    bf16* Vs = (bf16*)(smem + 16384);       // [128 d][64 k], swizzled
    bf16* Ps = (bf16*)(smem + 32768);       // per-wave [16 q][64 k], swizzled

    const int tid = threadIdx.x, wid = tid >> 6, lane = tid & 63;
    const int quad = lane >> 4, l16 = lane & 15;
    const int bh = blockIdx.x, b = bh >> 4, h = bh & 15;
    const int qt = gridDim.y - 1 - blockIdx.y;     // big tiles dispatched first
    const float scale = 0.08838834764831845f;      // 1/sqrt(128)

    // Q B-fragments, loop-invariant: lane l16 = q-row qt*64+wid*16+l16
    s16x8 qf[4];
    const bf16* qrow = q + ((size_t)(b * S + qt * 64 + wid * 16 + l16)) * D + h * 128;
    #pragma unroll
    for (int ks = 0; ks < 4; ++ks)
        qf[ks] = *(const s16x8*)(qrow + ks * 32 + quad * 8);

    f32x4 oacc[8] = {};                  // O^T: rows d = mt*16+quad*4+r, col q = l16
    float mstate = -INFINITY, lstate = 0.f;

    const bf16* kb0 = k + (size_t)(b * S) * D + h * 128;
    const bf16* vb0 = vt + (size_t)bh * 128 * S;
    bf16* psw = Ps + wid * 16 * 64;
    const int sw = l16 & 7;              // read-side swizzle key (row & 7)
    const int nch = qt + 1;

    for (int kc = 0; kc < nch; ++kc) {
        __syncthreads();
        #pragma unroll
        for (int c = 0; c < 4; ++c) {
            int choff = (wid * 4 + c) << 10;
            int off = choff + lane * 16;
            int rk = off >> 8, bk = (off & 255) >> 4;          // Ks: 256 B rows
            gload_lds16(kb0 + (size_t)(kc * 64 + rk) * D + ((bk ^ (rk & 7)) << 3),
                        (char*)Ks + choff);
            int rv = off >> 7, bv = (off & 127) >> 4;          // Vs: 128 B rows
            gload_lds16(vb0 + (size_t)rv * S + kc * 64 + ((bv ^ (rv & 7)) << 3),
                        (char*)Vs + choff);
        }
        __syncthreads();

        // S^T = K Q^T : wave computes 64 k x 16 q
        f32x4 sacc[4] = {};
        #pragma unroll
        for (int mt = 0; mt < 4; ++mt) {
            #pragma unroll
            for (int ks = 0; ks < 4; ++ks) {
                s16x8 kf = *(const s16x8*)(Ks + (mt * 16 + l16) * 128 +
                                           (((ks * 4 + quad) ^ sw) << 3));
                sacc[mt] = MFMA16(kf, qf[ks], sacc[mt]);
            }
        }

        const bool need_mask = (kc == qt);
        #pragma unroll
        for (int mt = 0; mt < 4; ++mt)
            #pragma unroll
            for (int r = 0; r < 4; ++r) {
                float vv = sacc[mt][r] * scale;
                if (need_mask) {
                    int kl = mt * 16 + quad * 4 + r;           // k local
                    if (kl > wid * 16 + l16) vv = -INFINITY;   // q local
                }
                sacc[mt][r] = vv;
            }

        // online softmax: lane owns q-col l16; 16 in-lane vals + xor16/xor32
        float mx = fmaxf(fmaxf(fmaxf(sacc[0][0], sacc[0][1]), fmaxf(sacc[0][2], sacc[0][3])),
                         fmaxf(fmaxf(sacc[1][0], sacc[1][1]), fmaxf(sacc[1][2], sacc[1][3])));
        mx = fmaxf(mx, fmaxf(fmaxf(fmaxf(sacc[2][0], sacc[2][1]), fmaxf(sacc[2][2], sacc[2][3])),
                             fmaxf(fmaxf(sacc[3][0], sacc[3][1]), fmaxf(sacc[3][2], sacc[3][3]))));
        mx = fmaxf(mx, __shfl_xor(mx, 16, 64));
        mx = fmaxf(mx, __shfl_xor(mx, 32, 64));
        float mnew = fmaxf(mstate, mx);
        float alpha = __expf(mstate - mnew);
        float rs = 0.f;
        #pragma unroll
        for (int mt = 0; mt < 4; ++mt)
            #pragma unroll
            for (int r = 0; r < 4; ++r) {
                float p = __expf(sacc[mt][r] - mnew);
                sacc[mt][r] = p;
                rs += p;
            }
        rs += __shfl_xor(rs, 16, 64);
        rs += __shfl_xor(rs, 32, 64);
        lstate = lstate * alpha + rs;
        mstate = mnew;
        #pragma unroll
        for (int mt = 0; mt < 8; ++mt)
            #pragma unroll
            for (int r = 0; r < 4; ++r) oacc[mt][r] *= alpha;

        // P^T -> Ps rows q=l16, swizzled 16B blocks (wave-private region)
        #pragma unroll
        for (int mt = 0; mt < 4; ++mt)
            #pragma unroll
            for (int r = 0; r < 4; ++r) {
                int kl = mt * 16 + quad * 4 + r;
                psw[l16 * 64 + (((kl >> 3) ^ sw) << 3) + (kl & 7)] =
                    __float2bfloat16(sacc[mt][r]);
            }

        // O^T += V^T P^T : A = V^T frag, B = P frag
        #pragma unroll
        for (int ks2 = 0; ks2 < 2; ++ks2) {
            s16x8 pf = *(const s16x8*)(psw + l16 * 64 + (((ks2 * 4 + quad) ^ sw) << 3));
            #pragma unroll
            for (int mt = 0; mt < 8; ++mt) {
                s16x8 vf = *(const s16x8*)(Vs + (mt * 16 + l16) * 64 +
                                           (((ks2 * 4 + quad) ^ sw) << 3));
                oacc[mt] = MFMA16(vf, pf, oacc[mt]);
            }
        }
    }

    // epilogue: transpose O^T -> O via LDS (alias whole smem), coalesced store
    float inv = 1.0f / lstate;
    __syncthreads();                       // all PV reads done before alias write
    float* osw = (float*)smem + wid * 16 * 130;
    #pragma unroll
    for (int mt = 0; mt < 8; ++mt)
        #pragma unroll
        for (int r = 0; r < 4; ++r)
            osw[l16 * 130 + mt * 16 + quad * 4 + r] = oacc[mt][r] * inv;
    float* obase = o + (size_t)(b * S + qt * 64 + wid * 16) * D + h * 128;
    #pragma unroll
    for (int r16 = 0; r16 < 16; ++r16) {
        float2 val = *(const float2*)(osw + r16 * 130 + lane * 2);
        *(float2*)(obase + (size_t)r16 * D + lane * 2) = val;
    }
}

// ---------------- LayerNorm over D=2048 (optional add, dual f32/bf16 out) ----------------
__global__ __launch_bounds__(256) void ln_kernel(
    const float* __restrict__ a, const float* __restrict__ b,
    float* __restrict__ outf, bf16* __restrict__ outb, int D)
{
    int row = blockIdx.x;
    const float* pa = a + (size_t)row * D;
    const float* pb = b ? b + (size_t)row * D : nullptr;
    float v[8];
    float sum = 0.f, sq = 0.f;
    #pragma unroll
    for (int u = 0; u < 8; ++u) {
        int j = threadIdx.x + u * 256;
        float x = pa[j];
        if (pb) x += pb[j];
        v[u] = x; sum += x; sq += x * x;
    }
    #pragma unroll
    for (int off = 32; off > 0; off >>= 1) {
        sum += __shfl_down(sum, off, 64);
        sq  += __shfl_down(sq,  off, 64);
    }
    __shared__ float red[8];
    int wid = threadIdx.x >> 6, lane = threadIdx.x & 63;
    if (lane == 0) { red[wid] = sum; red[4 + wid] = sq; }
    __syncthreads();
    sum = red[0] + red[1] + red[2] + red[3];
    sq  = red[4] + red[5] + red[6] + red[7];
    float mean = sum / D;
    float var = sq / D - mean * mean;
    float rstd = rsqrtf(fmaxf(var, 0.f) + 1e-5f);
    float* pof = outf ? outf + (size_t)row * D : nullptr;
    bf16* pob = outb ? outb + (size_t)row * D : nullptr;
    #pragma unroll
    for (int u = 0; u < 8; ++u) {
        int j = threadIdx.x + u * 256;
        float y = (v[u] - mean) * rstd;
        if (pof) pof[j] = y;
        if (pob) pob[j] = __float2bfloat16(y);
    }
}

// ---------------- launch ----------------
extern "C" void kernel_launch(void* const* d_in, const int* in_sizes, int n_in,
                              void* d_out, int out_size, void* d_ws, size_t ws_size,
                              hipStream_t stream) {
    const float* x  = (const float*)d_in[0];
    const float* Wq = (const float*)d_in[1];
    const float* Wk = (const float*)d_in[2];
    const float* Wv = (const float*)d_in[3];
    const float* W1 = (const float*)d_in[4];
    const float* b1 = (const float*)d_in[5];
    const float* W2 = (const float*)d_in[6];
    const float* b2 = (const float*)d_in[7];
    const float* sn = (const float*)d_in[8];
    const float* cs = (const float*)d_in[9];

    const int B = 2, S = 2048, D = 2048, H = 16, Dff = 8192;
    const int M = B * S;                       // 4096
    char* ws = (char*)d_ws;

    const size_t SB = (size_t)M * D * 2;       // 16 MB bf16 [M][D] slot
    const size_t o_xb   = 0;
    const size_t o_Wqt  = SB;
    const size_t o_Wkt  = o_Wqt + (size_t)D * D * 2;
    const size_t o_Wvt  = o_Wkt + (size_t)D * D * 2;
    const size_t o_qraw = o_Wvt + (size_t)D * D * 2;
    const size_t o_kraw = o_qraw + SB;
    const size_t o_vb   = o_qraw + 2 * SB;
    const size_t o_qr   = 0;                  // reuse xb
    const size_t o_kr   = SB;                 // reuse W bf16 region
    const size_t o_attn = o_qraw;             // fp32, reuse qraw+kraw
    const size_t o_vt   = o_vb + SB;
    const size_t o_outb = o_vt;               // reuse vt after attention
    const size_t o_outf = 0;                  // fp32, reuse qr+kr
    const size_t o_W1t  = o_vt + SB;
    const size_t o_W2t  = o_W1t + (size_t)D * Dff * 2;
    const size_t o_h    = o_W2t + (size_t)D * Dff * 2;

    // 1. conversions
    long nx = (long)M * D;
    cvt_f32_bf16<<<nx / 2048, 256, 0, stream>>>(x, (bf16*)(ws + o_xb), nx);
    transpose_cvt<<<dim3(D / 32, D / 32), 256, 0, stream>>>(Wq, (bf16*)(ws + o_Wqt), D, D);
    transpose_cvt<<<dim3(D / 32, D / 32), 256, 0, stream>>>(Wk, (bf16*)(ws + o_Wkt), D, D);
    transpose_cvt<<<dim3(D / 32, D / 32), 256, 0, stream>>>(Wv, (bf16*)(ws + o_Wvt), D, D);
    transpose_cvt<<<dim3(Dff / 32, D / 32), 256, 0, stream>>>(W1, (bf16*)(ws + o_W1t), D, Dff);
    transpose_cvt<<<dim3(D / 32, Dff / 32), 256, 0, stream>>>(W2, (bf16*)(ws + o_W2t), Dff, D);

    // 2. QKV projections
    dim3 gqkv(M / 128, D / 128);
    gemm_bt<0><<<gqkv, 256, 0, stream>>>((bf16*)(ws + o_xb), (bf16*)(ws + o_Wqt),
                                         ws + o_qraw, nullptr, nullptr, M, D, D);
    gemm_bt<0><<<gqkv, 256, 0, stream>>>((bf16*)(ws + o_xb), (bf16*)(ws + o_Wkt),
                                         ws + o_kraw, nullptr, nullptr, M, D, D);
    gemm_bt<0><<<gqkv, 256, 0, stream>>>((bf16*)(ws + o_xb), (bf16*)(ws + o_Wvt),
                                         ws + o_vb, nullptr, nullptr, M, D, D);

    // 3. RoPE + V transpose
    rope_kernel<<<M, 256, 0, stream>>>((bf16*)(ws + o_qraw), (bf16*)(ws + o_qr), sn, cs, S, D);
    rope_kernel<<<M, 256, 0, stream>>>((bf16*)(ws + o_kraw), (bf16*)(ws + o_kr), sn, cs, S, D);
    vtrans_kernel<<<dim3(S / 32, 4, B * H), 256, 0, stream>>>((bf16*)(ws + o_vb),
                                                              (bf16*)(ws + o_vt), S, D, H);

    // 4. causal flash attention (transposed-score form, 64-row q-tiles)
    attn_kernel<<<dim3(B * H, S / 64), 256, 0, stream>>>(
        (bf16*)(ws + o_qr), (bf16*)(ws + o_kr), (bf16*)(ws + o_vt),
        (float*)(ws + o_attn), S, D, H);

    // 5. LN(attn + x)
    ln_kernel<<<M, 256, 0, stream>>>((float*)(ws + o_attn), x,
                                     (float*)(ws + o_outf), (bf16*)(ws + o_outb), D);

    // 6. FFN1: gelu(out @ W1 + b1) -> bf16 h
    gemm_bt<1><<<dim3(M / 128, Dff / 128), 256, 0, stream>>>(
        (bf16*)(ws + o_outb), (bf16*)(ws + o_W1t), ws + o_h, b1, nullptr, M, Dff, D);

    // 7. FFN2: h @ W2 + b2 + out -> fp32 into d_out
    gemm_bt<2><<<dim3(M / 128, D / 128), 256, 0, stream>>>(
        (bf16*)(ws + o_h), (bf16*)(ws + o_W2t), d_out, b2, (float*)(ws + o_outf), M, D, Dff);

    // 8. LN2 in place on d_out
    ln_kernel<<<M, 256, 0, stream>>>((float*)d_out, nullptr, (float*)d_out, nullptr, D);
}

// Round 5
// 928.270 us; speedup vs baseline: 1.2682x; 1.0926x over previous
//
#include <hip/hip_runtime.h>
#include <hip/hip_bf16.h>
#include <math.h>
#include <stdint.h>

using bf16 = __hip_bfloat16;
typedef __attribute__((ext_vector_type(4))) float f32x4;
typedef __attribute__((ext_vector_type(8))) short s16x8;

#define MFMA16(a, b, c) __builtin_amdgcn_mfma_f32_16x16x32_bf16(a, b, c, 0, 0, 0)

__device__ __forceinline__ void gload_lds16(const void* g, void* l) {
    __builtin_amdgcn_global_load_lds(
        (const __attribute__((address_space(1))) void*)g,
        (__attribute__((address_space(3))) void*)l, 16, 0, 0);
}

// ---------------- fp32 -> bf16 straight convert (8 elems/thread) ----------------
struct alignas(16) bf16x8s { bf16 v[8]; };

__global__ void cvt_f32_bf16(const float* __restrict__ in, bf16* __restrict__ out, long n) {
    long i = ((long)blockIdx.x * 256 + threadIdx.x) * 8;
    if (i >= n) return;
    float4 a = *(const float4*)(in + i);
    float4 b = *(const float4*)(in + i + 4);
    bf16x8s r;
    r.v[0] = __float2bfloat16(a.x); r.v[1] = __float2bfloat16(a.y);
    r.v[2] = __float2bfloat16(a.z); r.v[3] = __float2bfloat16(a.w);
    r.v[4] = __float2bfloat16(b.x); r.v[5] = __float2bfloat16(b.y);
    r.v[6] = __float2bfloat16(b.z); r.v[7] = __float2bfloat16(b.w);
    *(bf16x8s*)(out + i) = r;
}

// ---------------- fp32 [K][N] -> bf16 [N][K] transpose-convert ----------------
__global__ void transpose_cvt(const float* __restrict__ W, bf16* __restrict__ Wt, int K, int N) {
    __shared__ bf16 t[32][33];
    int tx = threadIdx.x & 31, ty = threadIdx.x >> 5;
    int n0 = blockIdx.x * 32, k0 = blockIdx.y * 32;
    #pragma unroll
    for (int r = ty; r < 32; r += 8)
        t[r][tx] = __float2bfloat16(W[(size_t)(k0 + r) * N + n0 + tx]);
    __syncthreads();
    #pragma unroll
    for (int r = ty; r < 32; r += 8)
        Wt[(size_t)(n0 + r) * K + k0 + tx] = t[tx][r];
}

// ---------------- GEMM: C[M,N] = A[M,K(full)] * Bt[N,K]^T, bf16 in, fp32 acc ----
// EPI 0: bf16 store. EPI 1: bias+gelu -> bf16. EPI 2: bias+resid -> fp32.
// EPI 3: plain fp32 partial store to C + blockIdx.z*M*N (split-K over blockIdx.z).
template <int EPI, int SPLITK>
__global__ __launch_bounds__(256) void gemm_bt(
    const bf16* __restrict__ A, const bf16* __restrict__ Bt,
    void* __restrict__ C, const float* __restrict__ bias,
    const float* __restrict__ resid, int M, int N, int K)
{
    __shared__ __align__(16) bf16 As[128 * 32];
    __shared__ __align__(16) bf16 Bs[128 * 32];
    const int tid = threadIdx.x;
    const int wid = tid >> 6, lane = tid & 63;
    const int quad = lane >> 4, l16 = lane & 15;
    const int bm = blockIdx.x * 128, bn = blockIdx.y * 128;
    const int wm = (wid >> 1) * 64, wn = (wid & 1) * 64;
    const int KH = K / SPLITK;
    const int kbeg = blockIdx.z * KH, kend = kbeg + KH;

    f32x4 acc[4][4] = {};

    for (int k0 = kbeg; k0 < kend; k0 += 32) {
        __syncthreads();
        #pragma unroll
        for (int c = 0; c < 2; ++c) {
            int choff = (wid * 2 + c) << 10;
            int off = choff + lane * 16;
            int row = off >> 6;
            int col = (off & 63) >> 1;
            gload_lds16(A  + (size_t)(bm + row) * K + k0 + col, (char*)As + choff);
            gload_lds16(Bt + (size_t)(bn + row) * K + k0 + col, (char*)Bs + choff);
        }
        __syncthreads();
        s16x8 af[4], bfr[4];
        #pragma unroll
        for (int mt = 0; mt < 4; ++mt)
            af[mt] = *(const s16x8*)(As + (wm + mt * 16 + l16) * 32 + quad * 8);
        #pragma unroll
        for (int nt = 0; nt < 4; ++nt)
            bfr[nt] = *(const s16x8*)(Bs + (wn + nt * 16 + l16) * 32 + quad * 8);
        #pragma unroll
        for (int mt = 0; mt < 4; ++mt)
            #pragma unroll
            for (int nt = 0; nt < 4; ++nt)
                acc[mt][nt] = MFMA16(af[mt], bfr[nt], acc[mt][nt]);
    }

    float* Cp = (float*)C;
    if (EPI == 3) Cp += (size_t)blockIdx.z * M * N;

    #pragma unroll
    for (int mt = 0; mt < 4; ++mt) {
        #pragma unroll
        for (int nt = 0; nt < 4; ++nt) {
            #pragma unroll
            for (int r = 0; r < 4; ++r) {
                int row = bm + wm + mt * 16 + quad * 4 + r;
                int col = bn + wn + nt * 16 + l16;
                float v = acc[mt][nt][r];
                if (EPI == 0) {
                    ((bf16*)C)[(size_t)row * N + col] = __float2bfloat16(v);
                } else if (EPI == 1) {
                    float xx = v + bias[col];
                    float g = 0.5f * xx * (1.0f + erff(xx * 0.7071067811865475f));
                    ((bf16*)C)[(size_t)row * N + col] = __float2bfloat16(g);
                } else if (EPI == 2) {
                    ((float*)C)[(size_t)row * N + col] =
                        v + bias[col] + resid[(size_t)row * N + col];
                } else {
                    Cp[(size_t)row * N + col] = v;
                }
            }
        }
    }
}

// ---------------- RoPE (reference indexes sin/cos by BATCH, not position) --------
__global__ void rope_kernel(const bf16* __restrict__ in, bf16* __restrict__ out,
                            const float* __restrict__ sn, const float* __restrict__ cs,
                            int S, int D, int instride) {
    int row = blockIdx.x;
    int pos = row / S;                 // batch index — matches reference broadcast
    const int half = D >> 1;
    const bf16* r = in + (size_t)row * instride;
    bf16* o = out + (size_t)row * D;
    for (int j = threadIdx.x; j < half; j += 256) {
        uint32_t pr = *(const uint32_t*)(r + 2 * j);
        float x1 = __uint_as_float(pr << 16);
        float x2 = __uint_as_float(pr & 0xffff0000u);
        float c = cs[(size_t)pos * half + j], s = sn[(size_t)pos * half + j];
        o[j]        = __float2bfloat16(x1 * c - x2 * s);
        o[half + j] = __float2bfloat16(x1 * s + x2 * c);
    }
}

// ---------------- V transpose per head: v[b,s,h,d] (strided) -> vt[bh, d, s] -----
__global__ void vtrans_kernel(const bf16* __restrict__ v, bf16* __restrict__ vt,
                              int S, int D, int H, int instride) {
    __shared__ bf16 t[32][33];
    int bh = blockIdx.z, b = bh >> 4, h = bh & 15;
    int s0 = blockIdx.x * 32, d0 = blockIdx.y * 32;
    int tx = threadIdx.x & 31, ty = threadIdx.x >> 5;
    #pragma unroll
    for (int r = ty; r < 32; r += 8)
        t[r][tx] = v[(size_t)(b * S + s0 + r) * instride + h * 128 + d0 + tx];
    __syncthreads();
    #pragma unroll
    for (int r = ty; r < 32; r += 8)
        vt[((size_t)bh * 128 + d0 + r) * S + s0 + tx] = t[tx][r];
}

// ---------------- Flash attention, transposed-score form ----------------
__global__ __launch_bounds__(256, 4) void attn_kernel(
    const bf16* __restrict__ q, const bf16* __restrict__ k, const bf16* __restrict__ vt,
    float* __restrict__ o, int S, int D, int H)
{
    __shared__ __align__(16) char smem[40960];
    bf16* Ks = (bf16*)smem;                 // [64 k][128 d], 16B-block XOR swizzle
    bf16* Vs = (bf16*)(smem + 16384);       // [128 d][64 k], swizzled
    bf16* Ps = (bf16*)(smem + 32768);       // per-wave [16 q][64 k], swizzled

    const int tid = threadIdx.x, wid = tid >> 6, lane = tid & 63;
    const int quad = lane >> 4, l16 = lane & 15;
    const int bh = blockIdx.x, b = bh >> 4, h = bh & 15;
    const int qt = gridDim.y - 1 - blockIdx.y;     // big tiles dispatched first
    const float scale = 0.08838834764831845f;      // 1/sqrt(128)

    s16x8 qf[4];
    const bf16* qrow = q + ((size_t)(b * S + qt * 64 + wid * 16 + l16)) * D + h * 128;
    #pragma unroll
    for (int ks = 0; ks < 4; ++ks)
        qf[ks] = *(const s16x8*)(qrow + ks * 32 + quad * 8);

    f32x4 oacc[8] = {};
    float mstate = -INFINITY, lstate = 0.f;

    const bf16* kb0 = k + (size_t)(b * S) * D + h * 128;
    const bf16* vb0 = vt + (size_t)bh * 128 * S;
    bf16* psw = Ps + wid * 16 * 64;
    const int sw = l16 & 7;
    const int nch = qt + 1;

    for (int kc = 0; kc < nch; ++kc) {
        __syncthreads();
        #pragma unroll
        for (int c = 0; c < 4; ++c) {
            int choff = (wid * 4 + c) << 10;
            int off = choff + lane * 16;
            int rk = off >> 8, bk = (off & 255) >> 4;
            gload_lds16(kb0 + (size_t)(kc * 64 + rk) * D + ((bk ^ (rk & 7)) << 3),
                        (char*)Ks + choff);
            int rv = off >> 7, bv = (off & 127) >> 4;
            gload_lds16(vb0 + (size_t)rv * S + kc * 64 + ((bv ^ (rv & 7)) << 3),
                        (char*)Vs + choff);
        }
        __syncthreads();

        f32x4 sacc[4] = {};
        #pragma unroll
        for (int mt = 0; mt < 4; ++mt) {
            #pragma unroll
            for (int ks = 0; ks < 4; ++ks) {
                s16x8 kf = *(const s16x8*)(Ks + (mt * 16 + l16) * 128 +
                                           (((ks * 4 + quad) ^ sw) << 3));
                sacc[mt] = MFMA16(kf, qf[ks], sacc[mt]);
            }
        }

        const bool need_mask = (kc == qt);
        #pragma unroll
        for (int mt = 0; mt < 4; ++mt)
            #pragma unroll
            for (int r = 0; r < 4; ++r) {
                float vv = sacc[mt][r] * scale;
                if (need_mask) {
                    int kl = mt * 16 + quad * 4 + r;
                    if (kl > wid * 16 + l16) vv = -INFINITY;
                }
                sacc[mt][r] = vv;
            }

        float mx = fmaxf(fmaxf(fmaxf(sacc[0][0], sacc[0][1]), fmaxf(sacc[0][2], sacc[0][3])),
                         fmaxf(fmaxf(sacc[1][0], sacc[1][1]), fmaxf(sacc[1][2], sacc[1][3])));
        mx = fmaxf(mx, fmaxf(fmaxf(fmaxf(sacc[2][0], sacc[2][1]), fmaxf(sacc[2][2], sacc[2][3])),
                             fmaxf(fmaxf(sacc[3][0], sacc[3][1]), fmaxf(sacc[3][2], sacc[3][3]))));
        mx = fmaxf(mx, __shfl_xor(mx, 16, 64));
        mx = fmaxf(mx, __shfl_xor(mx, 32, 64));
        float mnew = fmaxf(mstate, mx);
        float alpha = __expf(mstate - mnew);
        float rs = 0.f;
        #pragma unroll
        for (int mt = 0; mt < 4; ++mt)
            #pragma unroll
            for (int r = 0; r < 4; ++r) {
                float p = __expf(sacc[mt][r] - mnew);
                sacc[mt][r] = p;
                rs += p;
            }
        rs += __shfl_xor(rs, 16, 64);
        rs += __shfl_xor(rs, 32, 64);
        lstate = lstate * alpha + rs;
        mstate = mnew;
        #pragma unroll
        for (int mt = 0; mt < 8; ++mt)
            #pragma unroll
            for (int r = 0; r < 4; ++r) oacc[mt][r] *= alpha;

        #pragma unroll
        for (int mt = 0; mt < 4; ++mt)
            #pragma unroll
            for (int r = 0; r < 4; ++r) {
                int kl = mt * 16 + quad * 4 + r;
                psw[l16 * 64 + (((kl >> 3) ^ sw) << 3) + (kl & 7)] =
                    __float2bfloat16(sacc[mt][r]);
            }

        #pragma unroll
        for (int ks2 = 0; ks2 < 2; ++ks2) {
            s16x8 pf = *(const s16x8*)(psw + l16 * 64 + (((ks2 * 4 + quad) ^ sw) << 3));
            #pragma unroll
            for (int mt = 0; mt < 8; ++mt) {
                s16x8 vf = *(const s16x8*)(Vs + (mt * 16 + l16) * 64 +
                                           (((ks2 * 4 + quad) ^ sw) << 3));
                oacc[mt] = MFMA16(vf, pf, oacc[mt]);
            }
        }
    }

    float inv = 1.0f / lstate;
    __syncthreads();
    float* osw = (float*)smem + wid * 16 * 130;
    #pragma unroll
    for (int mt = 0; mt < 8; ++mt)
        #pragma unroll
        for (int r = 0; r < 4; ++r)
            osw[l16 * 130 + mt * 16 + quad * 4 + r] = oacc[mt][r] * inv;
    float* obase = o + (size_t)(b * S + qt * 64 + wid * 16) * D + h * 128;
    #pragma unroll
    for (int r16 = 0; r16 < 16; ++r16) {
        float2 val = *(const float2*)(osw + r16 * 130 + lane * 2);
        *(float2*)(obase + (size_t)r16 * D + lane * 2) = val;
    }
}

// ---------------- LayerNorm over D=2048: x = a (+b) (+c) (+bias), dual out ------
__global__ __launch_bounds__(256) void ln_kernel(
    const float* __restrict__ a, const float* __restrict__ b,
    const float* __restrict__ c, const float* __restrict__ bias,
    float* __restrict__ outf, bf16* __restrict__ outb, int D)
{
    int row = blockIdx.x;
    const float* pa = a + (size_t)row * D;
    const float* pb = b ? b + (size_t)row * D : nullptr;
    const float* pc = c ? c + (size_t)row * D : nullptr;
    float v[8];
    float sum = 0.f, sq = 0.f;
    #pragma unroll
    for (int u = 0; u < 8; ++u) {
        int j = threadIdx.x + u * 256;
        float x = pa[j];
        if (pb) x += pb[j];
        if (pc) x += pc[j];
        if (bias) x += bias[j];
        v[u] = x; sum += x; sq += x * x;
    }
    #pragma unroll
    for (int off = 32; off > 0; off >>= 1) {
        sum += __shfl_down(sum, off, 64);
        sq  += __shfl_down(sq,  off, 64);
    }
    __shared__ float red[8];
    int wid = threadIdx.x >> 6, lane = threadIdx.x & 63;
    if (lane == 0) { red[wid] = sum; red[4 + wid] = sq; }
    __syncthreads();
    sum = red[0] + red[1] + red[2] + red[3];
    sq  = red[4] + red[5] + red[6] + red[7];
    float mean = sum / D;
    float var = sq / D - mean * mean;
    float rstd = rsqrtf(fmaxf(var, 0.f) + 1e-5f);
    float* pof = outf ? outf + (size_t)row * D : nullptr;
    bf16* pob = outb ? outb + (size_t)row * D : nullptr;
    #pragma unroll
    for (int u = 0; u < 8; ++u) {
        int j = threadIdx.x + u * 256;
        float y = (v[u] - mean) * rstd;
        if (pof) pof[j] = y;
        if (pob) pob[j] = __float2bfloat16(y);
    }
}

// ---------------- launch ----------------
// Workspace plan (proven budget: 232 MB, same as the R3 passing layout).
// Lifetime-ordered region reuse; weight transposes for W1/W2 are enqueued
// late so they can recycle dead regions.
//   [  0, 16) xb        -> qr (after QKV)   -> outb (after attn)
//   [ 16, 48) Wq^T/Wk^T -> kr@16-32         -> W1t (after LN1) -> W2t (after FFN1)
//   [ 32, 40) Wv^T      (dead after QKV)
//   [ 40, 88) qkv       -> attn fp32 @40-72 (after rope/vtrans)
//   [ 72,104) (qkv tail + vt@88-104) -> outf fp32 (after attn)
//   [104,168) h (FFN1 out, bf16 [M][8192])
//   [168,232) p0|p1 (FFN2 split-K fp32 partials)
extern "C" void kernel_launch(void* const* d_in, const int* in_sizes, int n_in,
                              void* d_out, int out_size, void* d_ws, size_t ws_size,
                              hipStream_t stream) {
    const float* x  = (const float*)d_in[0];
    const float* Wq = (const float*)d_in[1];
    const float* Wk = (const float*)d_in[2];
    const float* Wv = (const float*)d_in[3];
    const float* W1 = (const float*)d_in[4];
    const float* b1 = (const float*)d_in[5];
    const float* W2 = (const float*)d_in[6];
    const float* b2 = (const float*)d_in[7];
    const float* sn = (const float*)d_in[8];
    const float* cs = (const float*)d_in[9];

    const int B = 2, S = 2048, D = 2048, H = 16, Dff = 8192;
    const int M = B * S;                       // 4096
    const int NQKV = 3 * D;                    // 6144
    char* ws = (char*)d_ws;
    const size_t MB = 1024 * 1024;

    const size_t o_xb   = 0;                   // bf16 [M][D], 16 MB
    const size_t o_Wqkv = 16 * MB;             // bf16 [6144][2048], 24 MB
    const size_t o_qkv  = 40 * MB;             // bf16 [M][6144], 48 MB
    const size_t o_qr   = 0;                   // bf16 16 MB (xb dead)
    const size_t o_kr   = 16 * MB;             // bf16 16 MB (Wq^T/Wk^T dead)
    const size_t o_vt   = 88 * MB;             // bf16 [BH][128][S], 16 MB
    const size_t o_attn = 40 * MB;             // fp32 [M][D], 32 MB (qkv dead)
    const size_t o_outb = 0;                   // bf16 16 MB (qr dead)
    const size_t o_outf = 72 * MB;             // fp32 32 MB (qkv tail + vt dead)
    const size_t o_W1t  = 16 * MB;             // bf16 [8192][2048], 32 MB (kr/attn dead)
    const size_t o_h    = 104 * MB;            // bf16 [M][8192], 64 MB
    const size_t o_W2t  = 16 * MB;             // bf16 [2048][8192], 32 MB (W1t dead)
    const size_t o_p    = 168 * MB;            // fp32 2x[M][D], 64 MB

    // 1. x -> bf16; Wq/Wk/Wv -> stacked transposed bf16 [6144][2048]
    long nx = (long)M * D;
    cvt_f32_bf16<<<nx / 2048, 256, 0, stream>>>(x, (bf16*)(ws + o_xb), nx);
    transpose_cvt<<<dim3(D / 32, D / 32), 256, 0, stream>>>(
        Wq, (bf16*)(ws + o_Wqkv), D, D);
    transpose_cvt<<<dim3(D / 32, D / 32), 256, 0, stream>>>(
        Wk, (bf16*)(ws + o_Wqkv) + (size_t)D * D, D, D);
    transpose_cvt<<<dim3(D / 32, D / 32), 256, 0, stream>>>(
        Wv, (bf16*)(ws + o_Wqkv) + 2 * (size_t)D * D, D, D);

    // 2. fused QKV projection: [M][2048] x [6144][2048]^T -> [M][6144]
    gemm_bt<0, 1><<<dim3(M / 128, NQKV / 128), 256, 0, stream>>>(
        (bf16*)(ws + o_xb), (bf16*)(ws + o_Wqkv), ws + o_qkv, nullptr, nullptr,
        M, NQKV, D);

    // 3. RoPE + V transpose (strided reads from fused buffer)
    rope_kernel<<<M, 256, 0, stream>>>((bf16*)(ws + o_qkv), (bf16*)(ws + o_qr),
                                       sn, cs, S, D, NQKV);
    rope_kernel<<<M, 256, 0, stream>>>((bf16*)(ws + o_qkv) + D, (bf16*)(ws + o_kr),
                                       sn, cs, S, D, NQKV);
    vtrans_kernel<<<dim3(S / 32, 4, B * H), 256, 0, stream>>>(
        (bf16*)(ws + o_qkv) + 2 * D, (bf16*)(ws + o_vt), S, D, H, NQKV);

    // 4. causal flash attention -> fp32 [M][D]
    attn_kernel<<<dim3(B * H, S / 64), 256, 0, stream>>>(
        (bf16*)(ws + o_qr), (bf16*)(ws + o_kr), (bf16*)(ws + o_vt),
        (float*)(ws + o_attn), S, D, H);

    // 5. LN(attn + x) -> outf (fp32, residual for LN2) + outb (bf16, FFN1 input)
    ln_kernel<<<M, 256, 0, stream>>>((float*)(ws + o_attn), x, nullptr, nullptr,
                                     (float*)(ws + o_outf), (bf16*)(ws + o_outb), D);

    // 6. W1^T (late: reuses kr/attn regions), then FFN1: gelu(out@W1+b1) -> bf16 h
    transpose_cvt<<<dim3(Dff / 32, D / 32), 256, 0, stream>>>(
        W1, (bf16*)(ws + o_W1t), D, Dff);
    gemm_bt<1, 1><<<dim3(M / 128, Dff / 128), 256, 0, stream>>>(
        (bf16*)(ws + o_outb), (bf16*)(ws + o_W1t), ws + o_h, b1, nullptr, M, Dff, D);

    // 7. W2^T (late: reuses W1t region), then FFN2 split-K=2 -> p0|p1 fp32
    transpose_cvt<<<dim3(D / 32, Dff / 32), 256, 0, stream>>>(
        W2, (bf16*)(ws + o_W2t), Dff, D);
    gemm_bt<3, 2><<<dim3(M / 128, D / 128, 2), 256, 0, stream>>>(
        (bf16*)(ws + o_h), (bf16*)(ws + o_W2t), ws + o_p, nullptr, nullptr, M, D, Dff);

    // 8. LN2( p0 + p1 + outf + b2 ) -> d_out fp32
    ln_kernel<<<M, 256, 0, stream>>>((float*)(ws + o_p),
                                     (float*)(ws + o_p) + (size_t)M * D,
                                     (float*)(ws + o_outf), b2,
                                     (float*)d_out, nullptr, D);
}